// Round 18
// baseline (1749.746 us; speedup 1.0000x reference)
//
#include <hip/hip_runtime.h>
#include <stdint.h>

#define T_STEPS 1024
#define TC 128          // chunk length; 8 chunks
#define NCHUNK (T_STEPS/TC)
#define ROLL (2*TC+1)   // rolling h-history: 257 slots so rec(ch) writes never hit mlp(ch-1) reads
#define D_EMB 256
#define HID 256
#define VOCAB 32000
#define NACT 128
#define XDIM 768

typedef __attribute__((ext_vector_type(8))) short short8;
typedef __attribute__((ext_vector_type(4))) float f32x4;
typedef __attribute__((ext_vector_type(8))) int i32x8;
typedef unsigned short u16;
typedef unsigned int u32;
typedef unsigned char u8;

// exp2-domain gate scales: sigmoid(x)=1/(1+2^(-log2e*x)); tanh(x)=(2^(2log2e*x)-1)/(2^(2log2e*x)+1)
#define SGI (-1.4426950408889634f)
#define SGG ( 2.8853900817779268f)
#define KI (SGI/512.f)
#define KG (SGG/512.f)

#define HS 272          // h8 row stride (16B aligned for ds_read_b128)
#define HB (8*HS)       // one h8 buffer (8 real rows): 2176 B

__device__ __forceinline__ float bf2f(u16 u){
  union { u32 u; float f; } v; v.u = ((u32)u) << 16; return v.f;
}
__device__ __forceinline__ u16 f2bf(float f){
  union { float f; u32 u; } v; v.f = f;
  u32 u = v.u;
  return (u16)((u + 0x7FFFu + ((u >> 16) & 1u)) >> 16);
}
__device__ __forceinline__ void bf2x(u32 d, float& lo, float& hi){
  union { u32 u; float f; } a, b;
  a.u = d << 16; b.u = d & 0xffff0000u;
  lo = a.f; hi = b.f;
}
__device__ __forceinline__ float rcp_(float x){ return __builtin_amdgcn_rcpf(x); }
__device__ __forceinline__ float exp2_(float x){ return __builtin_amdgcn_exp2f(x); }
__device__ __forceinline__ ushort4 pack4(float4 v){
  ushort4 r; r.x=f2bf(v.x); r.y=f2bf(v.y); r.z=f2bf(v.z); r.w=f2bf(v.w); return r;
}
__device__ __forceinline__ u8 f2e4m3(float v){
  u32 p = __builtin_amdgcn_cvt_pk_fp8_f32(v, v, 0, false);
  return (u8)(p & 0xff);
}

// ---------------------------------------------------------------------------
// K0: weight prep. bf16 [N][K] transposes for gx/mlp; fp8 e4m3 [col][k]
// (scaled x32) for the recurrent Wh. W1 h-rows (k>=256) pre-scaled 1/16:
// roll stores 16*h.
// ---------------------------------------------------------------------------
__global__ void k_convert(const float* Wsx, const float* Wsh, const float* Whx, const float* Whh,
                          const float* W1, const float* W2,
                          u16* Wsxt, u16* Whxt, u8* Wsh8, u8* Whh8, u16* W1t, u16* W2t)
{
  const long NW = 1024L*256;
  const long NW1 = 256L*768;
  const long NW2 = 128L*256;
  const long total = 4*NW + NW1 + NW2;
  for (long i = blockIdx.x*(long)blockDim.x+threadIdx.x; i<total; i += (long)gridDim.x*blockDim.x){
    long j = i;
    if (j < NW){ long n=j>>8, k=j&255; Wsxt[j] = f2bf(Wsx[k*1024+n]); continue; } j -= NW;
    if (j < NW){ long n=j>>8, k=j&255; Whxt[j] = f2bf(Whx[k*1024+n]); continue; } j -= NW;
    if (j < NW){ long n=j>>8, k=j&255; Wsh8[j] = f2e4m3(Wsh[k*1024+n]*32.f); continue; } j -= NW;
    if (j < NW){ long n=j>>8, k=j&255; Whh8[j] = f2e4m3(Whh[k*1024+n]*32.f); continue; } j -= NW;
    if (j < NW1){ long n=j/768, k=j%768; float sc = (k>=256)?0.0625f:1.f;
                  W1t[j] = f2bf(W1[k*256+n]*sc); continue; } j -= NW1;
    { long n=j>>8, k=j&255; W2t[j] = f2bf(W2[k*128+n]); }
  }
}

// ---------------------------------------------------------------------------
// K_FUSED: one launch = rec(rec_cs) [blocks 0..15] + gx(gx_cs) [16..271]
// + mlp(mlp_cs) [272..399]. Roles are independent within a launch:
// gx writes gxnext_* (read by rec NEXT launch); mlp reads roll slots
// written by rec in PREVIOUS launches (ROLL=257 keeps windows disjoint).
// rec waves run at s_setprio(1). rec GEMM: MX-scaled fp8 MFMA 16x16x128
// (scales=1.0 via 0x7F). roll writes staged in LDS, bulk-flushed every
// 4 steps (double-buffered groups) so the per-barrier vmcnt(0) drain of
// global writes is paid once per 4 steps, not every step.
// ---------------------------------------------------------------------------
__global__ __launch_bounds__(512) void k_fused(
    const int* stack_ids, const int* buffer_ids, const int* action_ids,
    const float* wemb, const float* aemb,
    const u16* Wsxt, const u16* Whxt, const float* bs_, const float* bh_,
    const u8* Wsh8, const u8* Whh8,
    const u16* gxcur_s, const u16* gxcur_h,
    u16* gxnext_s, u16* gxnext_h,
    u16* roll_s, u16* roll_h, float* cst,
    const u16* W1t, const float* b1, const u16* W2t, const float* b2, float* out,
    int rec_cs, int gx_cs, int mlp_cs)
{
  __shared__ __attribute__((aligned(16))) char arena[51456];
  const int bid = blockIdx.x;
  const int tid = threadIdx.x;
  const int wave = tid>>6, lane = tid&63, quad = lane>>4, l16 = lane&15;

  if (bid < 16){
    // =====================================================================
    // REC: 16 blocks = 2 LSTMs x 8 batch-eighths (8 real rows; lanes 8..15
    // read A row l16&7 -> broadcast dup, no duplicate stores).
    // =====================================================================
    if (rec_cs < 0) return;
    __builtin_amdgcn_s_setprio(1);
    char* h8 = arena;                          // h8[2][8*HS] fp8, 4352 B
    u16* hstage = (u16*)(arena + 4352);        // [2 groups][4 slots][8][256] bf16, 32 KB
    const int lstm = bid>>3, bq = bid&7;
    const u8* Wh8 = lstm ? Whh8 : Wsh8;
    const u16* gxc = lstm ? gxcur_h : gxcur_s;
    u16* roll      = lstm ? roll_h : roll_s;
    const int w = wave;
    const int usub = quad>>1, rh = quad&1;
    const int rloc = rh*4;
    const int unit = w*32 + usub*16 + l16;
    float* cstp = cst + ((((size_t)lstm*8 + bq)*8 + w)*64 + lane)*4;

    // Stationary Wh fragments for 16x16x128: Bf8[ct][kh] = 32B of col,
    // k = kh*128 + quad*32 .. +32.
    i32x8 Bf8[8][2];
    #pragma unroll
    for (int ct=0; ct<8; ct++){
      int gate = ct & 3, usubB = ct >> 2;
      int col = gate*256 + w*32 + usubB*16 + l16;
      #pragma unroll
      for (int kh=0; kh<2; kh++){
        uint4* p = (uint4*)&Bf8[ct][kh];
        p[0] = *(const uint4*)(Wh8 + (size_t)col*256 + kh*128 + quad*32);
        p[1] = *(const uint4*)(Wh8 + (size_t)col*256 + kh*128 + quad*32 + 16);
      }
    }

    const size_t gxoff = (size_t)(bq>>1)*16384 + (size_t)unit*16 + (size_t)((bq&1)*8 + rloc);
    // flush indexing: this thread's 16-u16 segment within a 4-slot group
    const int fidx = tid*16;
    const int fslot = fidx>>11, frow = (fidx>>8)&7, fcol = fidx&255;

    float c[4];
    if (rec_cs == 0){
      #pragma unroll
      for (int i=0;i<4;i++) c[i] = 0.f;
      for (int i = tid; i < (2*HB)/4; i += 512) ((int*)h8)[i] = 0;
    } else {
      float4 cv = *(const float4*)cstp;
      c[0]=cv.x; c[1]=cv.y; c[2]=cv.z; c[3]=cv.w;
      int slot = (rec_cs-1)%ROLL;
      if (tid < 256){
        int row = tid>>5, seg = tid&31;   // 8 rows x 32 segs of 8 units
        #pragma unroll
        for (int q=0;q<8;q++){
          int un = seg*8+q;
          float hf = bf2f(roll[(size_t)slot*16384 + (bq*8+row)*256 + un]);
          h8[row*HS + un] = (char)f2e4m3(hf);
        }
      }
    }
    __syncthreads();

    int par = 0;
    for (int tc=0; tc<TC; tc++){
      const int t = rec_cs + tc;
      const u16* gxt = gxc + (size_t)tc*65536 + gxoff;
      uint2 gxr[4];
      #pragma unroll
      for (int g=0; g<4; g++)
        gxr[g] = *(const uint2*)(gxt + (size_t)g*4096);
      // bulk-flush the completed group (steps tc-4..tc-1) while MFMAs run
      if (tc && (tc&3)==0){
        int g = ((tc-4)>>2)&1;
        const u16* src = hstage + g*8192 + fidx;
        uint4 v0 = *(const uint4*)(src);
        uint4 v1 = *(const uint4*)(src + 8);
        int gslot = (rec_cs + tc-4 + fslot) % ROLL;
        u16* dst = roll + (size_t)gslot*16384 + (size_t)(bq*8+frow)*256 + fcol;
        *(uint4*)(dst)     = v0;
        *(uint4*)(dst + 8) = v1;
      }
      f32x4 acc[8];
      #pragma unroll
      for (int ct=0;ct<8;ct++) acc[ct] = (f32x4)(0.f);
      #pragma unroll
      for (int kh=0;kh<2;kh++){
        i32x8 a;
        uint4* ap = (uint4*)&a;
        ap[0] = *(const uint4*)&h8[par*HB + (l16&7)*HS + kh*128 + quad*32];
        ap[1] = *(const uint4*)&h8[par*HB + (l16&7)*HS + kh*128 + quad*32 + 16];
        #pragma unroll
        for (int ct=0;ct<8;ct++)
          acc[ct] = __builtin_amdgcn_mfma_scale_f32_16x16x128_f8f6f4(
                      a, Bf8[ct][kh], acc[ct], 0, 0,
                      0, 0x7F7F7F7F, 0, 0x7F7F7F7F);
      }
      f32x4 aI = usub ? acc[4] : acc[0];
      f32x4 aF = usub ? acc[5] : acc[1];
      f32x4 aG = usub ? acc[6] : acc[2];
      f32x4 aO = usub ? acc[7] : acc[3];
      float gf_[4][4];
      #pragma unroll
      for (int g=0; g<4; g++){
        bf2x(gxr[g].x, gf_[g][0], gf_[g][1]);
        bf2x(gxr[g].y, gf_[g][2], gf_[g][3]);
      }
      float h16v[4];
      #pragma unroll
      for (int i2=0;i2<4;i2++){
        float argI = fmaf(aI[i2], KI, gf_[0][i2]);
        float argF = fmaf(aF[i2], KI, gf_[1][i2]);
        float argG = fmaf(aG[i2], KG, gf_[2][i2]);
        float argO = fmaf(aO[i2], KI, gf_[3][i2]);
        float eI = exp2_(argI), eF = exp2_(argF), eG = exp2_(argG), eO = exp2_(argO);
        float sF  = rcp_(1.f + eF);
        float rIG = rcp_((1.f + eI)*(1.f + eG));
        float cc  = sF*c[i2] + (eG - 1.f)*rIG;
        c[i2] = cc;
        float eC  = exp2_(cc * SGG);
        float num = fmaf(eC, 16.f, -16.f);
        float den = (1.f + eO)*(1.f + eC);
        h16v[i2] = num * rcp_(den);
      }
      // stage bf16(16h) in LDS (group (tc>>2)&1, slot tc&3); fp8 to h8
      u16* sbase = hstage + (((tc>>2)&1)*8192) + ((tc&3)*2048) + rloc*256 + unit;
      char* hbase = &h8[(par^1)*HB + rloc*HS + unit];
      #pragma unroll
      for (int p=0;p<2;p++){
        u32 pkb;
        asm("v_cvt_pk_bf16_f32 %0, %1, %2" : "=v"(pkb) : "v"(h16v[p*2]), "v"(h16v[p*2+1]));
        sbase[(p*2)*256]   = (u16)(pkb & 0xffff);
        sbase[(p*2+1)*256] = (u16)(pkb >> 16);
        u32 pk8 = __builtin_amdgcn_cvt_pk_fp8_f32(h16v[p*2], h16v[p*2+1], 0, false);
        hbase[(p*2)*HS]   = (char)(pk8 & 0xff);
        hbase[(p*2+1)*HS] = (char)((pk8 >> 8) & 0xff);
      }
      __syncthreads();
      par ^= 1;
    }
    // final flush: last group (steps TC-4..TC-1)
    {
      int g = ((TC-4)>>2)&1;
      const u16* src = hstage + g*8192 + fidx;
      uint4 v0 = *(const uint4*)(src);
      uint4 v1 = *(const uint4*)(src + 8);
      int gslot = (rec_cs + TC-4 + fslot) % ROLL;
      u16* dst = roll + (size_t)gslot*16384 + (size_t)(bq*8+frow)*256 + fcol;
      *(uint4*)(dst)     = v0;
      *(uint4*)(dst + 8) = v1;
    }
    { float4 cv; cv.x=c[0]; cv.y=c[1]; cv.z=c[2]; cv.w=c[3]; *(float4*)cstp = cv; }

  } else if (bid < 272){
    // =====================================================================
    // GX (512 thr, 8 waves): gx = (emb[ids[:,t]] @ Wx + bias) * gate_scale,
    // exp2-domain pre-scale. Writes gxnext_* for the NEXT chunk.
    // =====================================================================
    if (gx_cs < 0) return;
    const int gid = bid - 16;
    const int tc = gid & 127, lstm = gid >> 7;
    const int t = gx_cs + tc;
    const int* ids = lstm ? action_ids : stack_ids;
    const float* emb = lstm ? aemb : wemb;
    const u16* Wxt = lstm ? Whxt : Wsxt;
    const float* bias = lstm ? bh_ : bs_;
    u16* gxc = (lstm ? gxnext_h : gxnext_s) + (size_t)tc*65536;
    u16* Ab = (u16*)arena;                 // [64][264]
    int* sids = (int*)(arena + 33792);

    if (tid < 64) sids[tid] = ids[tid*T_STEPS + t];
    __syncthreads();
    #pragma unroll
    for (int i=0;i<8;i++){
      int v = i*512 + tid; int b = v>>6, f0 = (v&63)*4;
      float4 ld = *(const float4*)(emb + (size_t)sids[b]*256 + f0);
      *(ushort4*)&Ab[b*264 + f0] = pack4(ld);
    }
    __syncthreads();

    for (int nc=0; nc<4; nc++){
      f32x4 acc[4][2];
      #pragma unroll
      for (int r=0;r<4;r++){ acc[r][0]=(f32x4)(0.f); acc[r][1]=(f32x4)(0.f); }
      #pragma unroll
      for (int kk=0;kk<8;kk++){
        short8 a[4], bfr[2];
        #pragma unroll
        for (int r=0;r<4;r++) a[r] = *(const short8*)&Ab[(r*16+l16)*264 + kk*32 + quad*8];
        #pragma unroll
        for (int cc=0;cc<2;cc++){
          int n = nc*256 + wave*32 + cc*16 + l16;
          bfr[cc] = *(const short8*)(Wxt + (size_t)n*256 + kk*32 + quad*8);
        }
        #pragma unroll
        for (int r=0;r<4;r++)
          #pragma unroll
          for (int cc=0;cc<2;cc++)
            acc[r][cc] = __builtin_amdgcn_mfma_f32_16x16x32_bf16(a[r], bfr[cc], acc[r][cc], 0,0,0);
      }
      #pragma unroll
      for (int cc=0;cc<2;cc++){
        int col = nc*256 + wave*32 + cc*16 + l16;
        float bv = bias[col];
        float sgm = ((col >> 8) == 2) ? SGG : SGI;
        #pragma unroll
        for (int r=0;r<4;r++){
          ushort4 o;
          o.x = f2bf((acc[r][cc][0]+bv)*sgm); o.y = f2bf((acc[r][cc][1]+bv)*sgm);
          o.z = f2bf((acc[r][cc][2]+bv)*sgm); o.w = f2bf((acc[r][cc][3]+bv)*sgm);
          *(ushort4*)&gxc[((size_t)r*1024 + col)*16 + quad*4] = o;
        }
      }
    }

  } else {
    // =====================================================================
    // MLP (512 thr, 8 waves): fused MLP + log-softmax + NLL for chunk
    // mlp_cs (written by rec in previous launches; ROLL=257 guards races).
    // =====================================================================
    if (mlp_cs < 0) return;
    const int t = mlp_cs + (bid - 272);
    u16* Axb = (u16*)arena;              // [64][136]
    u16* lgb = (u16*)arena;              // [64][132] (aliases Axb)
    u16* y1b = (u16*)(arena + 17408);    // [64][264]
    int* sids = (int*)(arena + 51200);

    if (tid < 64) sids[tid] = buffer_ids[tid*T_STEPS + t];

    f32x4 acc1[2][4];
    #pragma unroll
    for (int nc=0;nc<2;nc++)
      #pragma unroll
      for (int r=0;r<4;r++) acc1[nc][r] = (f32x4)(0.f);

    for (int kc=0; kc<6; kc++){
      __syncthreads();
      if (kc < 2){
        #pragma unroll
        for (int i=0;i<4;i++){
          int v = i*512+tid; int b = v>>5, seg = v&31;
          float4 ld = *(const float4*)(wemb + (size_t)sids[b]*256 + kc*128 + seg*4);
          *(ushort4*)&Axb[b*136 + seg*4] = pack4(ld);
        }
      } else {
        const u16* roll = (kc < 4) ? roll_h : roll_s;
        int half = kc & 1;
        if (t == 0){
          uint4 z = make_uint4(0,0,0,0);
          #pragma unroll
          for (int i=0;i<2;i++){
            int v = i*512+tid; int b = v>>4, seg = v&15;
            *(uint4*)&Axb[b*136 + seg*8] = z;
          }
        } else {
          int slot = (t-1) % ROLL;
          #pragma unroll
          for (int i=0;i<2;i++){
            int v = i*512+tid; int b = v>>4, seg = v&15;
            *(uint4*)&Axb[b*136 + seg*8] =
              *(const uint4*)(roll + (size_t)slot*16384 + b*256 + half*128 + seg*8);
          }
        }
      }
      __syncthreads();
      #pragma unroll
      for (int nc=0;nc<2;nc++){
        int n = nc*128 + wave*16 + l16;
        #pragma unroll
        for (int kk=0;kk<4;kk++){
          short8 a[4];
          #pragma unroll
          for (int r=0;r<4;r++) a[r] = *(const short8*)&Axb[(r*16+l16)*136 + kk*32 + quad*8];
          short8 bb = *(const short8*)(W1t + (size_t)n*768 + kc*128 + kk*32 + quad*8);
          #pragma unroll
          for (int r=0;r<4;r++)
            acc1[nc][r] = __builtin_amdgcn_mfma_f32_16x16x32_bf16(a[r], bb, acc1[nc][r], 0,0,0);
        }
      }
    }
    // layer1 epilogue: relu -> y1b
    #pragma unroll
    for (int nc=0;nc<2;nc++){
      int col = nc*128 + wave*16 + l16;
      float bv = b1[col];
      #pragma unroll
      for (int r=0;r<4;r++)
        #pragma unroll
        for (int i2=0;i2<4;i2++){
          int row = r*16 + quad*4 + i2;
          float y = acc1[nc][r][i2] + bv;
          y1b[row*264 + col] = f2bf(y > 0.f ? y : 0.f);
        }
    }
    __syncthreads();
    // layer2: logits = y1 @ W2 + b2 (one 16-col tile per wave)
    f32x4 acc2[4];
    #pragma unroll
    for (int r=0;r<4;r++) acc2[r] = (f32x4)(0.f);
    const int n2 = wave*16 + l16;
    #pragma unroll
    for (int kk=0;kk<8;kk++){
      short8 a[4];
      #pragma unroll
      for (int r=0;r<4;r++) a[r] = *(const short8*)&y1b[(r*16+l16)*264 + kk*32 + quad*8];
      short8 bb = *(const short8*)(W2t + (size_t)n2*256 + kk*32 + quad*8);
      #pragma unroll
      for (int r=0;r<4;r++)
        acc2[r] = __builtin_amdgcn_mfma_f32_16x16x32_bf16(a[r], bb, acc2[r], 0,0,0);
    }
    {
      float bv = b2[n2];
      #pragma unroll
      for (int r=0;r<4;r++)
        #pragma unroll
        for (int i2=0;i2<4;i2++)
          lgb[(r*16+quad*4+i2)*132 + n2] = f2bf(acc2[r][i2] + bv);
    }
    __syncthreads();
    // log-softmax + NLL: one batch row per lane of wave 0
    if (tid < 64){
      int b = tid;
      float m = -1e30f;
      for (int j=0;j<128;j++) m = fmaxf(m, bf2f(lgb[b*132+j]));
      float s = 0.f;
      for (int j=0;j<128;j++) s += __expf(bf2f(lgb[b*132+j]) - m);
      int tgt = action_ids[b*T_STEPS + t];
      float v = __logf(s) + m - bf2f(lgb[b*132 + tgt]);
      #pragma unroll
      for (int o=32;o>0;o>>=1) v += __shfl_down(v, o);
      if (tid == 0) atomicAdd(out, v);
    }
  }
}

// ---------------------------------------------------------------------------
extern "C" void kernel_launch(void* const* d_in, const int* in_sizes, int n_in,
                              void* d_out, int out_size, void* d_ws, size_t ws_size,
                              hipStream_t stream)
{
  (void)in_sizes; (void)n_in; (void)out_size; (void)ws_size;
  const int* stack_ids  = (const int*)d_in[0];
  const int* buffer_ids = (const int*)d_in[1];
  const int* action_ids = (const int*)d_in[2];
  const float* word_emb   = (const float*)d_in[3];
  const float* action_emb = (const float*)d_in[4];
  const float* Wsx = (const float*)d_in[5];
  const float* Wsh = (const float*)d_in[6];
  const float* bs  = (const float*)d_in[7];
  const float* Whx = (const float*)d_in[8];
  const float* Whh = (const float*)d_in[9];
  const float* bh  = (const float*)d_in[10];
  const float* W1  = (const float*)d_in[11];
  const float* b1  = (const float*)d_in[12];
  const float* W2  = (const float*)d_in[13];
  const float* b2  = (const float*)d_in[14];
  float* out = (float*)d_out;

  char* ws = (char*)d_ws;
  size_t off = 0;
  auto alloc = [&](size_t bytes){ char* p = ws + off; off += (bytes + 255) & ~(size_t)255; return p; };
  u16* Wsxt = (u16*)alloc(1024*256*2);
  u16* Whxt = (u16*)alloc(1024*256*2);
  u8*  Wsh8 = (u8*)alloc(1024*256);
  u8*  Whh8 = (u8*)alloc(1024*256);
  u16* W1t  = (u16*)alloc(256*768*2);
  u16* W2t  = (u16*)alloc(128*256*2);
  u16* gxc_s[2], *gxc_h[2];
  gxc_s[0] = (u16*)alloc((size_t)TC*65536*2);        // 16.8 MB each
  gxc_s[1] = (u16*)alloc((size_t)TC*65536*2);
  gxc_h[0] = (u16*)alloc((size_t)TC*65536*2);
  gxc_h[1] = (u16*)alloc((size_t)TC*65536*2);
  u16* roll_s = (u16*)alloc((size_t)ROLL*64*256*2);  // 8.4 MB (16*h bf16)
  u16* roll_h = (u16*)alloc((size_t)ROLL*64*256*2);
  float* cst  = (float*)alloc(2*8*8*64*4*4);         // c-state [lstm][bq8][w][lane][4]

  (void)hipMemsetAsync(out, 0, sizeof(float), stream);
  k_convert<<<512, 256, 0, stream>>>(Wsx, Wsh, Whx, Whh, W1, W2,
                                     Wsxt, Whxt, Wsh8, Whh8, W1t, W2t);
  // prologue: gx(chunk 0) only -> gxc[0]
  k_fused<<<400, 512, 0, stream>>>(stack_ids, buffer_ids, action_ids, word_emb, action_emb,
      Wsxt, Whxt, bs, bh, Wsh8, Whh8,
      gxc_s[0], gxc_h[0], gxc_s[0], gxc_h[0],
      roll_s, roll_h, cst, W1t, b1, W2t, b2, out,
      -1, 0, -1);
  for (int ch=0; ch<NCHUNK; ch++){
    int cs = ch*TC;
    int gx_cs  = (ch+1 < NCHUNK) ? (ch+1)*TC : -1;
    int mlp_cs = (ch > 0) ? (ch-1)*TC : -1;
    k_fused<<<400, 512, 0, stream>>>(stack_ids, buffer_ids, action_ids, word_emb, action_emb,
        Wsxt, Whxt, bs, bh, Wsh8, Whh8,
        gxc_s[ch&1], gxc_h[ch&1], gxc_s[(ch+1)&1], gxc_h[(ch+1)&1],
        roll_s, roll_h, cst, W1t, b1, W2t, b2, out,
        cs, gx_cs, mlp_cs);
  }
  // epilogue: mlp(chunk 7) only
  k_fused<<<400, 512, 0, stream>>>(stack_ids, buffer_ids, action_ids, word_emb, action_emb,
      Wsxt, Whxt, bs, bh, Wsh8, Whh8,
      gxc_s[0], gxc_h[0], gxc_s[0], gxc_h[0],
      roll_s, roll_h, cst, W1t, b1, W2t, b2, out,
      -1, -1, (NCHUNK-1)*TC);
}

// Round 20
// 1347.776 us; speedup vs baseline: 1.2982x; 1.2982x over previous
//
#include <hip/hip_runtime.h>
#include <stdint.h>

#define T_STEPS 1024
#define TC 128          // chunk length; 8 chunks
#define NCHUNK (T_STEPS/TC)
#define ROLL (2*TC+1)   // rolling h-history: 257 slots so rec(ch) writes never hit mlp(ch-1) reads
#define D_EMB 256
#define HID 256
#define VOCAB 32000
#define NACT 128
#define XDIM 768

typedef __attribute__((ext_vector_type(8))) short short8;
typedef __attribute__((ext_vector_type(4))) float f32x4;
typedef __attribute__((ext_vector_type(8))) int i32x8;
typedef unsigned short u16;
typedef unsigned int u32;
typedef unsigned char u8;

// exp2-domain gate scales: sigmoid(x)=1/(1+2^(-log2e*x)); tanh(x)=(2^(2log2e*x)-1)/(2^(2log2e*x)+1)
#define SGI (-1.4426950408889634f)
#define SGG ( 2.8853900817779268f)
#define KI (SGI/512.f)
#define KG (SGG/512.f)

#define HS 272          // h8 row stride (16B aligned for ds_read_b128)
#define HB (8*HS)       // one h8 buffer (8 real rows): 2176 B

__device__ __forceinline__ float bf2f(u16 u){
  union { u32 u; float f; } v; v.u = ((u32)u) << 16; return v.f;
}
__device__ __forceinline__ u16 f2bf(float f){
  union { float f; u32 u; } v; v.f = f;
  u32 u = v.u;
  return (u16)((u + 0x7FFFu + ((u >> 16) & 1u)) >> 16);
}
__device__ __forceinline__ void bf2x(u32 d, float& lo, float& hi){
  union { u32 u; float f; } a, b;
  a.u = d << 16; b.u = d & 0xffff0000u;
  lo = a.f; hi = b.f;
}
__device__ __forceinline__ float rcp_(float x){ return __builtin_amdgcn_rcpf(x); }
__device__ __forceinline__ float exp2_(float x){ return __builtin_amdgcn_exp2f(x); }
__device__ __forceinline__ ushort4 pack4(float4 v){
  ushort4 r; r.x=f2bf(v.x); r.y=f2bf(v.y); r.z=f2bf(v.z); r.w=f2bf(v.w); return r;
}
__device__ __forceinline__ u8 f2e4m3(float v){
  u32 p = __builtin_amdgcn_cvt_pk_fp8_f32(v, v, 0, false);
  return (u8)(p & 0xff);
}

// ---------------------------------------------------------------------------
// K0: weight prep. bf16 [N][K] transposes for gx/mlp; fp8 e4m3 [col][k]
// (scaled x32) for the recurrent Wh. W1 h-rows (k>=256) pre-scaled 1/16:
// roll stores 16*h.
// ---------------------------------------------------------------------------
__global__ void k_convert(const float* Wsx, const float* Wsh, const float* Whx, const float* Whh,
                          const float* W1, const float* W2,
                          u16* Wsxt, u16* Whxt, u8* Wsh8, u8* Whh8, u16* W1t, u16* W2t)
{
  const long NW = 1024L*256;
  const long NW1 = 256L*768;
  const long NW2 = 128L*256;
  const long total = 4*NW + NW1 + NW2;
  for (long i = blockIdx.x*(long)blockDim.x+threadIdx.x; i<total; i += (long)gridDim.x*blockDim.x){
    long j = i;
    if (j < NW){ long n=j>>8, k=j&255; Wsxt[j] = f2bf(Wsx[k*1024+n]); continue; } j -= NW;
    if (j < NW){ long n=j>>8, k=j&255; Whxt[j] = f2bf(Whx[k*1024+n]); continue; } j -= NW;
    if (j < NW){ long n=j>>8, k=j&255; Wsh8[j] = f2e4m3(Wsh[k*1024+n]*32.f); continue; } j -= NW;
    if (j < NW){ long n=j>>8, k=j&255; Whh8[j] = f2e4m3(Whh[k*1024+n]*32.f); continue; } j -= NW;
    if (j < NW1){ long n=j/768, k=j%768; float sc = (k>=256)?0.0625f:1.f;
                  W1t[j] = f2bf(W1[k*256+n]*sc); continue; } j -= NW1;
    { long n=j>>8, k=j&255; W2t[j] = f2bf(W2[k*128+n]); }
  }
}

// ---------------------------------------------------------------------------
// K_FUSED: one launch = rec(rec_cs) [blocks 0..15] + gx(gx_cs) [16..271]
// + mlp(mlp_cs) [272..399]. Roles are independent within a launch:
// gx writes gxnext_* (read by rec NEXT launch); mlp reads roll slots
// written by rec in PREVIOUS launches (ROLL=257 keeps windows disjoint).
// rec waves run at s_setprio(1). rec GEMM: MX-scaled fp8 MFMA 16x16x128
// (scales=1.0 via 0x7F). roll writes: direct per-step global stores
// (round-15 scheme; LDS staging measured SLOWER in r18). h8 holds 8 real
// rows only: lanes 8..15 broadcast-read row l16&7 (same-address LDS reads
// are conflict-free), removing duplicate row stores.
// ---------------------------------------------------------------------------
__global__ __launch_bounds__(512) void k_fused(
    const int* stack_ids, const int* buffer_ids, const int* action_ids,
    const float* wemb, const float* aemb,
    const u16* Wsxt, const u16* Whxt, const float* bs_, const float* bh_,
    const u8* Wsh8, const u8* Whh8,
    const u16* gxcur_s, const u16* gxcur_h,
    u16* gxnext_s, u16* gxnext_h,
    u16* roll_s, u16* roll_h, float* cst,
    const u16* W1t, const float* b1, const u16* W2t, const float* b2, float* out,
    int rec_cs, int gx_cs, int mlp_cs)
{
  __shared__ __attribute__((aligned(16))) char arena[51456];
  const int bid = blockIdx.x;
  const int tid = threadIdx.x;
  const int wave = tid>>6, lane = tid&63, quad = lane>>4, l16 = lane&15;

  if (bid < 16){
    // =====================================================================
    // REC: 16 blocks = 2 LSTMs x 8 batch-eighths (8 real rows; MFMA A rows
    // 8..15 are broadcast duplicates via read addressing).
    // =====================================================================
    if (rec_cs < 0) return;
    __builtin_amdgcn_s_setprio(1);
    char* h8 = arena;                       // h8[2][8*HS] fp8, 4352 B
    const int lstm = bid>>3, bq = bid&7;
    const u8* Wh8 = lstm ? Whh8 : Wsh8;
    const u16* gxc = lstm ? gxcur_h : gxcur_s;
    u16* roll      = lstm ? roll_h : roll_s;
    const int w = wave;
    const int usub = quad>>1, rh = quad&1;
    const int rloc = rh*4;
    const int unit = w*32 + usub*16 + l16;
    float* cstp = cst + ((((size_t)lstm*8 + bq)*8 + w)*64 + lane)*4;

    // Stationary Wh fragments for 16x16x128: Bf8[ct][kh] = 32B of col,
    // k = kh*128 + quad*32 .. +32.
    i32x8 Bf8[8][2];
    #pragma unroll
    for (int ct=0; ct<8; ct++){
      int gate = ct & 3, usubB = ct >> 2;
      int col = gate*256 + w*32 + usubB*16 + l16;
      #pragma unroll
      for (int kh=0; kh<2; kh++){
        uint4* p = (uint4*)&Bf8[ct][kh];
        p[0] = *(const uint4*)(Wh8 + (size_t)col*256 + kh*128 + quad*32);
        p[1] = *(const uint4*)(Wh8 + (size_t)col*256 + kh*128 + quad*32 + 16);
      }
    }

    const size_t gxoff = (size_t)(bq>>1)*16384 + (size_t)unit*16 + (size_t)((bq&1)*8 + rloc);

    float c[4];
    if (rec_cs == 0){
      #pragma unroll
      for (int i=0;i<4;i++) c[i] = 0.f;
      for (int i = tid; i < (2*HB)/4; i += 512) ((int*)h8)[i] = 0;
    } else {
      float4 cv = *(const float4*)cstp;
      c[0]=cv.x; c[1]=cv.y; c[2]=cv.z; c[3]=cv.w;
      int slot = (rec_cs-1)%ROLL;
      #pragma unroll
      for (int i=0;i<4;i++){
        int idx = i*512 + tid;
        if (idx < 2048){
          int row = idx>>8, un = idx&255;   // rows 0..7
          float hf = bf2f(roll[(size_t)slot*16384 + (bq*8+row)*256 + un]);
          h8[row*HS + un] = (char)f2e4m3(hf);
        }
      }
    }
    __syncthreads();

    int par = 0;
    for (int tc=0; tc<TC; tc++){
      const int t = rec_cs + tc;
      const u16* gxt = gxc + (size_t)tc*65536 + gxoff;
      uint2 gxr[4];
      #pragma unroll
      for (int g=0; g<4; g++)
        gxr[g] = *(const uint2*)(gxt + (size_t)g*4096);
      f32x4 acc[8];
      #pragma unroll
      for (int ct=0;ct<8;ct++) acc[ct] = (f32x4)(0.f);
      #pragma unroll
      for (int kh=0;kh<2;kh++){
        i32x8 a;
        uint4* ap = (uint4*)&a;
        ap[0] = *(const uint4*)&h8[par*HB + (l16&7)*HS + kh*128 + quad*32];
        ap[1] = *(const uint4*)&h8[par*HB + (l16&7)*HS + kh*128 + quad*32 + 16];
        #pragma unroll
        for (int ct=0;ct<8;ct++)
          acc[ct] = __builtin_amdgcn_mfma_scale_f32_16x16x128_f8f6f4(
                      a, Bf8[ct][kh], acc[ct], 0, 0,
                      0, 0x7F7F7F7F, 0, 0x7F7F7F7F);
      }
      f32x4 aI = usub ? acc[4] : acc[0];
      f32x4 aF = usub ? acc[5] : acc[1];
      f32x4 aG = usub ? acc[6] : acc[2];
      f32x4 aO = usub ? acc[7] : acc[3];
      float gf_[4][4];
      #pragma unroll
      for (int g=0; g<4; g++){
        bf2x(gxr[g].x, gf_[g][0], gf_[g][1]);
        bf2x(gxr[g].y, gf_[g][2], gf_[g][3]);
      }
      float h16v[4];
      #pragma unroll
      for (int i2=0;i2<4;i2++){
        float argI = fmaf(aI[i2], KI, gf_[0][i2]);
        float argF = fmaf(aF[i2], KI, gf_[1][i2]);
        float argG = fmaf(aG[i2], KG, gf_[2][i2]);
        float argO = fmaf(aO[i2], KI, gf_[3][i2]);
        float eI = exp2_(argI), eF = exp2_(argF), eG = exp2_(argG), eO = exp2_(argO);
        float sF  = rcp_(1.f + eF);
        float rIG = rcp_((1.f + eI)*(1.f + eG));
        float cc  = sF*c[i2] + (eG - 1.f)*rIG;
        c[i2] = cc;
        float eC  = exp2_(cc * SGG);
        float num = fmaf(eC, 16.f, -16.f);
        float den = (1.f + eO)*(1.f + eC);
        h16v[i2] = num * rcp_(den);
      }
      const int slot_w = t % ROLL;
      u16* rbase = roll + (size_t)slot_w*16384 + (size_t)(bq*8 + rloc)*256 + unit;
      char* hbase = &h8[(par^1)*HB + rloc*HS + unit];
      #pragma unroll
      for (int p=0;p<2;p++){
        u32 pkb;
        asm("v_cvt_pk_bf16_f32 %0, %1, %2" : "=v"(pkb) : "v"(h16v[p*2]), "v"(h16v[p*2+1]));
        rbase[(p*2)*256]   = (u16)(pkb & 0xffff);
        rbase[(p*2+1)*256] = (u16)(pkb >> 16);
        u32 pk8 = __builtin_amdgcn_cvt_pk_fp8_f32(h16v[p*2], h16v[p*2+1], 0, false);
        hbase[(p*2)*HS]   = (char)(pk8 & 0xff);
        hbase[(p*2+1)*HS] = (char)((pk8 >> 8) & 0xff);
      }
      __syncthreads();
      par ^= 1;
    }
    { float4 cv; cv.x=c[0]; cv.y=c[1]; cv.z=c[2]; cv.w=c[3]; *(float4*)cstp = cv; }

  } else if (bid < 272){
    // =====================================================================
    // GX (512 thr, 8 waves): gx = (emb[ids[:,t]] @ Wx + bias) * gate_scale,
    // exp2-domain pre-scale. Writes gxnext_* for the NEXT chunk.
    // =====================================================================
    if (gx_cs < 0) return;
    const int gid = bid - 16;
    const int tc = gid & 127, lstm = gid >> 7;
    const int t = gx_cs + tc;
    const int* ids = lstm ? action_ids : stack_ids;
    const float* emb = lstm ? aemb : wemb;
    const u16* Wxt = lstm ? Whxt : Wsxt;
    const float* bias = lstm ? bh_ : bs_;
    u16* gxc = (lstm ? gxnext_h : gxnext_s) + (size_t)tc*65536;
    u16* Ab = (u16*)arena;                 // [64][264]
    int* sids = (int*)(arena + 33792);

    if (tid < 64) sids[tid] = ids[tid*T_STEPS + t];
    __syncthreads();
    #pragma unroll
    for (int i=0;i<8;i++){
      int v = i*512 + tid; int b = v>>6, f0 = (v&63)*4;
      float4 ld = *(const float4*)(emb + (size_t)sids[b]*256 + f0);
      *(ushort4*)&Ab[b*264 + f0] = pack4(ld);
    }
    __syncthreads();

    for (int nc=0; nc<4; nc++){
      f32x4 acc[4][2];
      #pragma unroll
      for (int r=0;r<4;r++){ acc[r][0]=(f32x4)(0.f); acc[r][1]=(f32x4)(0.f); }
      #pragma unroll
      for (int kk=0;kk<8;kk++){
        short8 a[4], bfr[2];
        #pragma unroll
        for (int r=0;r<4;r++) a[r] = *(const short8*)&Ab[(r*16+l16)*264 + kk*32 + quad*8];
        #pragma unroll
        for (int cc=0;cc<2;cc++){
          int n = nc*256 + wave*32 + cc*16 + l16;
          bfr[cc] = *(const short8*)(Wxt + (size_t)n*256 + kk*32 + quad*8);
        }
        #pragma unroll
        for (int r=0;r<4;r++)
          #pragma unroll
          for (int cc=0;cc<2;cc++)
            acc[r][cc] = __builtin_amdgcn_mfma_f32_16x16x32_bf16(a[r], bfr[cc], acc[r][cc], 0,0,0);
      }
      #pragma unroll
      for (int cc=0;cc<2;cc++){
        int col = nc*256 + wave*32 + cc*16 + l16;
        float bv = bias[col];
        float sgm = ((col >> 8) == 2) ? SGG : SGI;
        #pragma unroll
        for (int r=0;r<4;r++){
          ushort4 o;
          o.x = f2bf((acc[r][cc][0]+bv)*sgm); o.y = f2bf((acc[r][cc][1]+bv)*sgm);
          o.z = f2bf((acc[r][cc][2]+bv)*sgm); o.w = f2bf((acc[r][cc][3]+bv)*sgm);
          *(ushort4*)&gxc[((size_t)r*1024 + col)*16 + quad*4] = o;
        }
      }
    }

  } else {
    // =====================================================================
    // MLP (512 thr, 8 waves): fused MLP + log-softmax + NLL for chunk
    // mlp_cs (written by rec in previous launches; ROLL=257 guards races).
    // =====================================================================
    if (mlp_cs < 0) return;
    const int t = mlp_cs + (bid - 272);
    u16* Axb = (u16*)arena;              // [64][136]
    u16* lgb = (u16*)arena;              // [64][132] (aliases Axb)
    u16* y1b = (u16*)(arena + 17408);    // [64][264]
    int* sids = (int*)(arena + 51200);

    if (tid < 64) sids[tid] = buffer_ids[tid*T_STEPS + t];

    f32x4 acc1[2][4];
    #pragma unroll
    for (int nc=0;nc<2;nc++)
      #pragma unroll
      for (int r=0;r<4;r++) acc1[nc][r] = (f32x4)(0.f);

    for (int kc=0; kc<6; kc++){
      __syncthreads();
      if (kc < 2){
        #pragma unroll
        for (int i=0;i<4;i++){
          int v = i*512+tid; int b = v>>5, seg = v&31;
          float4 ld = *(const float4*)(wemb + (size_t)sids[b]*256 + kc*128 + seg*4);
          *(ushort4*)&Axb[b*136 + seg*4] = pack4(ld);
        }
      } else {
        const u16* roll = (kc < 4) ? roll_h : roll_s;
        int half = kc & 1;
        if (t == 0){
          uint4 z = make_uint4(0,0,0,0);
          #pragma unroll
          for (int i=0;i<2;i++){
            int v = i*512+tid; int b = v>>4, seg = v&15;
            *(uint4*)&Axb[b*136 + seg*8] = z;
          }
        } else {
          int slot = (t-1) % ROLL;
          #pragma unroll
          for (int i=0;i<2;i++){
            int v = i*512+tid; int b = v>>4, seg = v&15;
            *(uint4*)&Axb[b*136 + seg*8] =
              *(const uint4*)(roll + (size_t)slot*16384 + b*256 + half*128 + seg*8);
          }
        }
      }
      __syncthreads();
      #pragma unroll
      for (int nc=0;nc<2;nc++){
        int n = nc*128 + wave*16 + l16;
        #pragma unroll
        for (int kk=0;kk<4;kk++){
          short8 a[4];
          #pragma unroll
          for (int r=0;r<4;r++) a[r] = *(const short8*)&Axb[(r*16+l16)*136 + kk*32 + quad*8];
          short8 bb = *(const short8*)(W1t + (size_t)n*768 + kc*128 + kk*32 + quad*8);
          #pragma unroll
          for (int r=0;r<4;r++)
            acc1[nc][r] = __builtin_amdgcn_mfma_f32_16x16x32_bf16(a[r], bb, acc1[nc][r], 0,0,0);
        }
      }
    }
    // layer1 epilogue: relu -> y1b
    #pragma unroll
    for (int nc=0;nc<2;nc++){
      int col = nc*128 + wave*16 + l16;
      float bv = b1[col];
      #pragma unroll
      for (int r=0;r<4;r++)
        #pragma unroll
        for (int i2=0;i2<4;i2++){
          int row = r*16 + quad*4 + i2;
          float y = acc1[nc][r][i2] + bv;
          y1b[row*264 + col] = f2bf(y > 0.f ? y : 0.f);
        }
    }
    __syncthreads();
    // layer2: logits = y1 @ W2 + b2 (one 16-col tile per wave)
    f32x4 acc2[4];
    #pragma unroll
    for (int r=0;r<4;r++) acc2[r] = (f32x4)(0.f);
    const int n2 = wave*16 + l16;
    #pragma unroll
    for (int kk=0;kk<8;kk++){
      short8 a[4];
      #pragma unroll
      for (int r=0;r<4;r++) a[r] = *(const short8*)&y1b[(r*16+l16)*264 + kk*32 + quad*8];
      short8 bb = *(const short8*)(W2t + (size_t)n2*256 + kk*32 + quad*8);
      #pragma unroll
      for (int r=0;r<4;r++)
        acc2[r] = __builtin_amdgcn_mfma_f32_16x16x32_bf16(a[r], bb, acc2[r], 0,0,0);
    }
    {
      float bv = b2[n2];
      #pragma unroll
      for (int r=0;r<4;r++)
        #pragma unroll
        for (int i2=0;i2<4;i2++)
          lgb[(r*16+quad*4+i2)*132 + n2] = f2bf(acc2[r][i2] + bv);
    }
    __syncthreads();
    // log-softmax + NLL: one batch row per lane of wave 0
    if (tid < 64){
      int b = tid;
      float m = -1e30f;
      for (int j=0;j<128;j++) m = fmaxf(m, bf2f(lgb[b*132+j]));
      float s = 0.f;
      for (int j=0;j<128;j++) s += __expf(bf2f(lgb[b*132+j]) - m);
      int tgt = action_ids[b*T_STEPS + t];
      float v = __logf(s) + m - bf2f(lgb[b*132 + tgt]);
      #pragma unroll
      for (int o=32;o>0;o>>=1) v += __shfl_down(v, o);
      if (tid == 0) atomicAdd(out, v);
    }
  }
}

// ---------------------------------------------------------------------------
extern "C" void kernel_launch(void* const* d_in, const int* in_sizes, int n_in,
                              void* d_out, int out_size, void* d_ws, size_t ws_size,
                              hipStream_t stream)
{
  (void)in_sizes; (void)n_in; (void)out_size; (void)ws_size;
  const int* stack_ids  = (const int*)d_in[0];
  const int* buffer_ids = (const int*)d_in[1];
  const int* action_ids = (const int*)d_in[2];
  const float* word_emb   = (const float*)d_in[3];
  const float* action_emb = (const float*)d_in[4];
  const float* Wsx = (const float*)d_in[5];
  const float* Wsh = (const float*)d_in[6];
  const float* bs  = (const float*)d_in[7];
  const float* Whx = (const float*)d_in[8];
  const float* Whh = (const float*)d_in[9];
  const float* bh  = (const float*)d_in[10];
  const float* W1  = (const float*)d_in[11];
  const float* b1  = (const float*)d_in[12];
  const float* W2  = (const float*)d_in[13];
  const float* b2  = (const float*)d_in[14];
  float* out = (float*)d_out;

  char* ws = (char*)d_ws;
  size_t off = 0;
  auto alloc = [&](size_t bytes){ char* p = ws + off; off += (bytes + 255) & ~(size_t)255; return p; };
  u16* Wsxt = (u16*)alloc(1024*256*2);
  u16* Whxt = (u16*)alloc(1024*256*2);
  u8*  Wsh8 = (u8*)alloc(1024*256);
  u8*  Whh8 = (u8*)alloc(1024*256);
  u16* W1t  = (u16*)alloc(256*768*2);
  u16* W2t  = (u16*)alloc(128*256*2);
  u16* gxc_s[2], *gxc_h[2];
  gxc_s[0] = (u16*)alloc((size_t)TC*65536*2);        // 16.8 MB each
  gxc_s[1] = (u16*)alloc((size_t)TC*65536*2);
  gxc_h[0] = (u16*)alloc((size_t)TC*65536*2);
  gxc_h[1] = (u16*)alloc((size_t)TC*65536*2);
  u16* roll_s = (u16*)alloc((size_t)ROLL*64*256*2);  // 8.4 MB (16*h bf16)
  u16* roll_h = (u16*)alloc((size_t)ROLL*64*256*2);
  float* cst  = (float*)alloc(2*8*8*64*4*4);         // c-state [lstm][bq8][w][lane][4]

  (void)hipMemsetAsync(out, 0, sizeof(float), stream);
  k_convert<<<512, 256, 0, stream>>>(Wsx, Wsh, Whx, Whh, W1, W2,
                                     Wsxt, Whxt, Wsh8, Whh8, W1t, W2t);
  // prologue: gx(chunk 0) only -> gxc[0]
  k_fused<<<400, 512, 0, stream>>>(stack_ids, buffer_ids, action_ids, word_emb, action_emb,
      Wsxt, Whxt, bs, bh, Wsh8, Whh8,
      gxc_s[0], gxc_h[0], gxc_s[0], gxc_h[0],
      roll_s, roll_h, cst, W1t, b1, W2t, b2, out,
      -1, 0, -1);
  for (int ch=0; ch<NCHUNK; ch++){
    int cs = ch*TC;
    int gx_cs  = (ch+1 < NCHUNK) ? (ch+1)*TC : -1;
    int mlp_cs = (ch > 0) ? (ch-1)*TC : -1;
    k_fused<<<400, 512, 0, stream>>>(stack_ids, buffer_ids, action_ids, word_emb, action_emb,
        Wsxt, Whxt, bs, bh, Wsh8, Whh8,
        gxc_s[ch&1], gxc_h[ch&1], gxc_s[(ch+1)&1], gxc_h[(ch+1)&1],
        roll_s, roll_h, cst, W1t, b1, W2t, b2, out,
        cs, gx_cs, mlp_cs);
  }
  // epilogue: mlp(chunk 7) only
  k_fused<<<400, 512, 0, stream>>>(stack_ids, buffer_ids, action_ids, word_emb, action_emb,
      Wsxt, Whxt, bs, bh, Wsh8, Whh8,
      gxc_s[0], gxc_h[0], gxc_s[0], gxc_h[0],
      roll_s, roll_h, cst, W1t, b1, W2t, b2, out,
      -1, -1, (NCHUNK-1)*TC);
}